// Round 8
// baseline (90.377 us; speedup 1.0000x reference)
//
#include <hip/hip_runtime.h>

#define NPOSE  262144
#define NCHAIN (NPOSE * 2)        // two independent FK chains per pose
#define BLOCK  64                 // single-wave blocks: no __syncthreads anywhere
#define TPB    4                  // tiles of 64 chains per block, sequential
#define NBLK   (NCHAIN / (64 * TPB))   // 2048 blocks = 8/CU exactly
#define CNT_OFF 8192              // byte offset of counter in d_ws (after 2048 partials)

typedef __attribute__((address_space(1))) void glb_void_t;
typedef __attribute__((address_space(3))) void lds_void_t;

// One FK step: 3x3 row-major elements e0..e8, cols c0=(e0,e3,e6),
// c1=(e1,e4,e7), t=(e2,e5,e8), R=[cross(c0,c1)|c0|c1]: v <- t + R*v
__device__ __forceinline__ void fk_step(float e0, float e1, float e2,
                                        float e3, float e4, float e5,
                                        float e6, float e7, float e8,
                                        float& v0, float& v1, float& v2) {
    const float x0 = e3 * e7 - e6 * e4;
    const float x1 = e6 * e1 - e0 * e7;
    const float x2 = e0 * e4 - e3 * e1;
    const float w0 = e2 + x0 * v0 + e0 * v1 + e1 * v2;
    const float w1 = e5 + x1 * v0 + e3 * v1 + e4 * v2;
    const float w2 = e8 + x2 * v0 + e6 * v1 + e7 * v2;
    v0 = w0; v1 = w1; v2 = w2;
}

// Chain of 4 matrices packed as 9 float4. translation = t0+R0*(t1+R1*(t2+R2*t3)).
// By-value scalars only: no local arrays / pointers into aggregates (no scratch).
__device__ __forceinline__ void chain_translation_q(
        float4 q0, float4 q1, float4 q2, float4 q3, float4 q4,
        float4 q5, float4 q6, float4 q7, float4 q8,
        float& v0, float& v1, float& v2) {
    v0 = q7.y; v1 = q8.x; v2 = q8.w;                       // t3 = (p29,p32,p35)
    fk_step(q4.z, q4.w, q5.x, q5.y, q5.z, q5.w, q6.x, q6.y, q6.z, v0, v1, v2);  // m2
    fk_step(q2.y, q2.z, q2.w, q3.x, q3.y, q3.z, q3.w, q4.x, q4.y, v0, v1, v2);  // m1
    fk_step(q0.x, q0.y, q0.z, q0.w, q1.x, q1.y, q1.z, q1.w, q2.x, v0, v1, v2);  // m0
}

__global__ __launch_bounds__(BLOCK) void fk_loss_fused(const float* __restrict__ outp,
                                                       const float* __restrict__ gtp,
                                                       float* __restrict__ partials,
                                                       unsigned int* __restrict__ counter,
                                                       float* __restrict__ out) {
    // Linear float4 LDS (global_load_lds dest = uniform base + lane*16).
    __shared__ float4 ldsA[64 * 9];        // 9216 B
    __shared__ float4 ldsB[64 * 9];        // 9216 B -> 18432 total, 8 blocks/CU
    const int t = threadIdx.x;
    const float4* __restrict__ g0 = reinterpret_cast<const float4*>(outp);
    const float4* __restrict__ g1 = reinterpret_cast<const float4*>(gtp);

    float acc = 0.0f;
#pragma unroll
    for (int it = 0; it < TPB; ++it) {
        const size_t tile = (size_t)blockIdx.x * TPB + it;
        const float4* pa = g0 + tile * 576 + t;
        const float4* pb = g1 + tile * 576 + t;
        if (it > 0)  // prior tile's ds_reads must drain before DMA overwrites LDS
            asm volatile("s_waitcnt lgkmcnt(0)" ::: "memory");
#pragma unroll
        for (int i = 0; i < 9; ++i)
            __builtin_amdgcn_global_load_lds((glb_void_t*)(pa + 64 * i),
                                             (lds_void_t*)(&ldsA[i * 64]), 16, 0, 0);
#pragma unroll
        for (int i = 0; i < 9; ++i)
            __builtin_amdgcn_global_load_lds((glb_void_t*)(pb + 64 * i),
                                             (lds_void_t*)(&ldsB[i * 64]), 16, 0, 0);

        asm volatile("s_waitcnt vmcnt(9)" ::: "memory");   // A landed; B still flying
        float tax, tay, taz;
        {
            const float4 r0 = ldsA[t * 9 + 0], r1 = ldsA[t * 9 + 1], r2 = ldsA[t * 9 + 2],
                         r3 = ldsA[t * 9 + 3], r4 = ldsA[t * 9 + 4], r5 = ldsA[t * 9 + 5],
                         r6 = ldsA[t * 9 + 6], r7 = ldsA[t * 9 + 7], r8 = ldsA[t * 9 + 8];
            chain_translation_q(r0, r1, r2, r3, r4, r5, r6, r7, r8, tax, tay, taz);
        }
        asm volatile("s_waitcnt vmcnt(0)" ::: "memory");   // B landed
        float tgx, tgy, tgz;
        {
            const float4 r0 = ldsB[t * 9 + 0], r1 = ldsB[t * 9 + 1], r2 = ldsB[t * 9 + 2],
                         r3 = ldsB[t * 9 + 3], r4 = ldsB[t * 9 + 4], r5 = ldsB[t * 9 + 5],
                         r6 = ldsB[t * 9 + 6], r7 = ldsB[t * 9 + 7], r8 = ldsB[t * 9 + 8];
            chain_translation_q(r0, r1, r2, r3, r4, r5, r6, r7, r8, tgx, tgy, tgz);
        }
        const float d0 = tax - tgx, d1 = tay - tgy, d2 = taz - tgz;
        acc += d0 * d0 + d1 * d1 + d2 * d2;
    }

    // wave reduction
#pragma unroll
    for (int off = 32; off > 0; off >>= 1)
        acc += __shfl_down(acc, off, 64);

    int lastflag = 0;
    if (t == 0) {
        partials[blockIdx.x] = acc;
        __threadfence();                               // release partial
        lastflag = (atomicAdd(counter, 1u) == NBLK - 1u) ? 1 : 0;
    }
    lastflag = __shfl(lastflag, 0, 64);

    if (lastflag) {
        __threadfence();                               // acquire all partials
        const float4* __restrict__ p4 = reinterpret_cast<const float4*>(partials); // 512 float4
        // 8 independent loads per lane -> all in flight; fixed order -> deterministic
        float4 v0 = p4[t +   0], v1 = p4[t +  64], v2 = p4[t + 128], v3 = p4[t + 192],
               v4 = p4[t + 256], v5 = p4[t + 320], v6 = p4[t + 384], v7 = p4[t + 448];
        float s = ((v0.x + v0.y) + (v0.z + v0.w)) + ((v1.x + v1.y) + (v1.z + v1.w))
                + ((v2.x + v2.y) + (v2.z + v2.w)) + ((v3.x + v3.y) + (v3.z + v3.w))
                + ((v4.x + v4.y) + (v4.z + v4.w)) + ((v5.x + v5.y) + (v5.z + v5.w))
                + ((v6.x + v6.y) + (v6.z + v6.w)) + ((v7.x + v7.y) + (v7.z + v7.w));
#pragma unroll
        for (int off = 32; off > 0; off >>= 1)
            s += __shfl_down(s, off, 64);
        if (t == 0) {
            const float mean = s / (262144.0f * 6.0f);
            out[0] = mean;  // pos_loss
            out[1] = mean;  // vel_loss == pos_loss (gt_prev cancels algebraically)
            atomicExch(counter, 0u);                   // clean for next replay
        }
    }
}

extern "C" void kernel_launch(void* const* d_in, const int* in_sizes, int n_in,
                              void* d_out, int out_size, void* d_ws, size_t ws_size,
                              hipStream_t stream) {
    const float* output_pose = (const float*)d_in[0];
    const float* gt_pose     = (const float*)d_in[1];
    // d_in[2] (gt_prev_pose) cancels algebraically: vel_loss == pos_loss.
    float* out = (float*)d_out;
    float* partials = (float*)d_ws;                            // 2048 floats
    unsigned int* counter = (unsigned int*)((char*)d_ws + CNT_OFF);

    // Counter must be 0 at launch (d_ws is poisoned 0xAA once); kernel self-resets,
    // but memset every call keeps it deterministic. 4-byte async memset is graph-legal.
    hipMemsetAsync(counter, 0, sizeof(unsigned int), stream);
    fk_loss_fused<<<NBLK, BLOCK, 0, stream>>>(output_pose, gt_pose, partials, counter, out);
}

// Round 9
// 68.604 us; speedup vs baseline: 1.3174x; 1.3174x over previous
//
#include <hip/hip_runtime.h>

#define NPOSE  262144
#define NCHAIN (NPOSE * 2)        // two independent FK chains per pose
#define BLOCK  256                // 4 waves; 256 chains per block
#define NBLK   (NCHAIN / BLOCK)   // 2048 blocks -> 2 blocks/CU (LDS-limited), 8 waves/CU

typedef __attribute__((address_space(1))) void glb_void_t;
typedef __attribute__((address_space(3))) void lds_void_t;

// One FK step: 3x3 row-major elements e0..e8, cols c0=(e0,e3,e6),
// c1=(e1,e4,e7), t=(e2,e5,e8), R=[cross(c0,c1)|c0|c1]: v <- t + R*v
__device__ __forceinline__ void fk_step(float e0, float e1, float e2,
                                        float e3, float e4, float e5,
                                        float e6, float e7, float e8,
                                        float& v0, float& v1, float& v2) {
    const float x0 = e3 * e7 - e6 * e4;
    const float x1 = e6 * e1 - e0 * e7;
    const float x2 = e0 * e4 - e3 * e1;
    const float w0 = e2 + x0 * v0 + e0 * v1 + e1 * v2;
    const float w1 = e5 + x1 * v0 + e3 * v1 + e4 * v2;
    const float w2 = e8 + x2 * v0 + e6 * v1 + e7 * v2;
    v0 = w0; v1 = w1; v2 = w2;
}

// Chain of 4 matrices packed as 9 float4. translation = t0+R0*(t1+R1*(t2+R2*t3)).
// By-value scalars only: no local arrays / pointers into aggregates (no scratch).
__device__ __forceinline__ void chain_translation_q(
        float4 q0, float4 q1, float4 q2, float4 q3, float4 q4,
        float4 q5, float4 q6, float4 q7, float4 q8,
        float& v0, float& v1, float& v2) {
    v0 = q7.y; v1 = q8.x; v2 = q8.w;                       // t3 = (p29,p32,p35)
    fk_step(q4.z, q4.w, q5.x, q5.y, q5.z, q5.w, q6.x, q6.y, q6.z, v0, v1, v2);  // m2
    fk_step(q2.y, q2.z, q2.w, q3.x, q3.y, q3.z, q3.w, q4.x, q4.y, v0, v1, v2);  // m1
    fk_step(q0.x, q0.y, q0.z, q0.w, q1.x, q1.y, q1.z, q1.w, q2.x, v0, v1, v2);  // m0
}

__global__ __launch_bounds__(BLOCK) void fk_loss_fused(const float* __restrict__ outp,
                                                       const float* __restrict__ gtp,
                                                       float* __restrict__ out) {
    // Linear float4 LDS, rows of 9 float4 (144B) per chain.
    // DMA dest = wave-uniform base + lane*16 -> &lds[i*256 + wavebase].
    __shared__ float4 ldsA[BLOCK * 9];     // 36864 B
    __shared__ float4 ldsB[BLOCK * 9];     // 36864 B -> 73728 total, 2 blocks/CU
    const int t = threadIdx.x;
    const int wbase = t & ~63;             // wave-uniform within each wave
    const size_t base4 = (size_t)blockIdx.x * (BLOCK * 9);
    const float4* __restrict__ ga = reinterpret_cast<const float4*>(outp) + base4;
    const float4* __restrict__ gb = reinterpret_cast<const float4*>(gtp) + base4;

#pragma unroll
    for (int i = 0; i < 9; ++i) {
        __builtin_amdgcn_global_load_lds((glb_void_t*)(ga + i * BLOCK + t),
                                         (lds_void_t*)(&ldsA[i * BLOCK + wbase]), 16, 0, 0);
        __builtin_amdgcn_global_load_lds((glb_void_t*)(gb + i * BLOCK + t),
                                         (lds_void_t*)(&ldsB[i * BLOCK + wbase]), 16, 0, 0);
    }
    __syncthreads();   // each wave drains its own vmcnt before barrier -> all DMAs landed

    float tax, tay, taz;
    {
        const float4 r0 = ldsA[t * 9 + 0], r1 = ldsA[t * 9 + 1], r2 = ldsA[t * 9 + 2],
                     r3 = ldsA[t * 9 + 3], r4 = ldsA[t * 9 + 4], r5 = ldsA[t * 9 + 5],
                     r6 = ldsA[t * 9 + 6], r7 = ldsA[t * 9 + 7], r8 = ldsA[t * 9 + 8];
        chain_translation_q(r0, r1, r2, r3, r4, r5, r6, r7, r8, tax, tay, taz);
    }
    float tgx, tgy, tgz;
    {
        const float4 r0 = ldsB[t * 9 + 0], r1 = ldsB[t * 9 + 1], r2 = ldsB[t * 9 + 2],
                     r3 = ldsB[t * 9 + 3], r4 = ldsB[t * 9 + 4], r5 = ldsB[t * 9 + 5],
                     r6 = ldsB[t * 9 + 6], r7 = ldsB[t * 9 + 7], r8 = ldsB[t * 9 + 8];
        chain_translation_q(r0, r1, r2, r3, r4, r5, r6, r7, r8, tgx, tgy, tgz);
    }

    const float d0 = tax - tgx, d1 = tay - tgy, d2 = taz - tgz;
    float acc = d0 * d0 + d1 * d1 + d2 * d2;

    // wave reduction, then cross-wave via tiny LDS
#pragma unroll
    for (int off = 32; off > 0; off >>= 1)
        acc += __shfl_down(acc, off, 64);
    __shared__ float smem[4];
    const int lane = t & 63, wid = t >> 6;
    if (lane == 0) smem[wid] = acc;
    __syncthreads();
    if (t == 0) {
        const float s = (smem[0] + smem[1]) + (smem[2] + smem[3]);
        const float scaled = s * (1.0f / (262144.0f * 6.0f));
        // Device-scope fp32 atomics: no fence needed (nobody reads others' partials).
        // vel_loss == pos_loss (gt_prev cancels algebraically).
        atomicAdd(&out[0], scaled);
        atomicAdd(&out[1], scaled);
    }
}

extern "C" void kernel_launch(void* const* d_in, const int* in_sizes, int n_in,
                              void* d_out, int out_size, void* d_ws, size_t ws_size,
                              hipStream_t stream) {
    const float* output_pose = (const float*)d_in[0];
    const float* gt_pose     = (const float*)d_in[1];
    // d_in[2] (gt_prev_pose) cancels algebraically: vel_loss == pos_loss.
    float* out = (float*)d_out;

    // Accumulator outputs must start at zero every call (graph-legal async memset).
    hipMemsetAsync(out, 0, 2 * sizeof(float), stream);
    fk_loss_fused<<<NBLK, BLOCK, 0, stream>>>(output_pose, gt_pose, out);
}

// Round 10
// 52.658 us; speedup vs baseline: 1.7163x; 1.3028x over previous
//
#include <hip/hip_runtime.h>

#define NPOSE  262144
#define NCHAIN (NPOSE * 2)       // two independent FK chains per pose
#define BLOCK  64                // single-wave blocks: NO __syncthreads anywhere
#define TPB    8                 // tiles (of 64 chains) per block
#define NBLK   (NCHAIN / (64 * TPB))   // 1024 blocks = 4 blocks/CU (LDS-limited)

typedef __attribute__((address_space(1))) void glb_void_t;
typedef __attribute__((address_space(3))) void lds_void_t;

// One FK step: 3x3 row-major elements e0..e8, cols c0=(e0,e3,e6),
// c1=(e1,e4,e7), t=(e2,e5,e8), R=[cross(c0,c1)|c0|c1]: v <- t + R*v
__device__ __forceinline__ void fk_step(float e0, float e1, float e2,
                                        float e3, float e4, float e5,
                                        float e6, float e7, float e8,
                                        float& v0, float& v1, float& v2) {
    const float x0 = e3 * e7 - e6 * e4;
    const float x1 = e6 * e1 - e0 * e7;
    const float x2 = e0 * e4 - e3 * e1;
    const float w0 = e2 + x0 * v0 + e0 * v1 + e1 * v2;
    const float w1 = e5 + x1 * v0 + e3 * v1 + e4 * v2;
    const float w2 = e8 + x2 * v0 + e6 * v1 + e7 * v2;
    v0 = w0; v1 = w1; v2 = w2;
}

// Chain of 4 matrices packed as 9 float4. translation = t0+R0*(t1+R1*(t2+R2*t3)).
// By-value scalars only: no local arrays, no pointers into aggregates (no scratch).
__device__ __forceinline__ void chain_translation_q(
        float4 q0, float4 q1, float4 q2, float4 q3, float4 q4,
        float4 q5, float4 q6, float4 q7, float4 q8,
        float& v0, float& v1, float& v2) {
    v0 = q7.y; v1 = q8.x; v2 = q8.w;                       // t3 = (p29,p32,p35)
    fk_step(q4.z, q4.w, q5.x, q5.y, q5.z, q5.w, q6.x, q6.y, q6.z, v0, v1, v2);  // m2
    fk_step(q2.y, q2.z, q2.w, q3.x, q3.y, q3.z, q3.w, q4.x, q4.y, v0, v1, v2);  // m1
    fk_step(q0.x, q0.y, q0.z, q0.w, q1.x, q1.y, q1.z, q1.w, q2.x, v0, v1, v2);  // m0
}

__global__ __launch_bounds__(BLOCK) void fk_loss_fused(const float* __restrict__ outp,
                                                       const float* __restrict__ gtp,
                                                       float* __restrict__ out) {
    // Double-buffered DMA tiles: [buf][9 float4 rows x 64 chains], linear layout
    // (global_load_lds dest = wave-uniform base + lane*16). 36864 B -> 4 blocks/CU.
    __shared__ float4 ldsA[2][64 * 9];
    __shared__ float4 ldsB[2][64 * 9];
    const int t = threadIdx.x;
    const float4* __restrict__ g0 = reinterpret_cast<const float4*>(outp);
    const float4* __restrict__ g1 = reinterpret_cast<const float4*>(gtp);
    const int tile0 = blockIdx.x * TPB;

    auto issue = [&](int tile, int b) {
        const float4* pa = g0 + (size_t)tile * 576 + t;
        const float4* pb = g1 + (size_t)tile * 576 + t;
#pragma unroll
        for (int i = 0; i < 9; ++i) {
            __builtin_amdgcn_global_load_lds((glb_void_t*)(pa + 64 * i),
                                             (lds_void_t*)(&ldsA[b][i * 64]), 16, 0, 0);
            __builtin_amdgcn_global_load_lds((glb_void_t*)(pb + 64 * i),
                                             (lds_void_t*)(&ldsB[b][i * 64]), 16, 0, 0);
        }
    };

    float acc = 0.0f;
    issue(tile0, 0);                       // prologue: tile 0 in flight
#pragma unroll
    for (int it = 0; it < TPB; ++it) {
        const int b = it & 1;
        if (it < TPB - 1) {
            issue(tile0 + it + 1, b ^ 1);  // keep next tile's 18 DMAs in flight
            asm volatile("s_waitcnt vmcnt(18)" ::: "memory");  // current tile landed
        } else {
            asm volatile("s_waitcnt vmcnt(0)" ::: "memory");
        }
        float tax, tay, taz, tgx, tgy, tgz;
        {
            const float4 r0 = ldsA[b][t * 9 + 0], r1 = ldsA[b][t * 9 + 1], r2 = ldsA[b][t * 9 + 2],
                         r3 = ldsA[b][t * 9 + 3], r4 = ldsA[b][t * 9 + 4], r5 = ldsA[b][t * 9 + 5],
                         r6 = ldsA[b][t * 9 + 6], r7 = ldsA[b][t * 9 + 7], r8 = ldsA[b][t * 9 + 8];
            chain_translation_q(r0, r1, r2, r3, r4, r5, r6, r7, r8, tax, tay, taz);
        }
        {
            const float4 r0 = ldsB[b][t * 9 + 0], r1 = ldsB[b][t * 9 + 1], r2 = ldsB[b][t * 9 + 2],
                         r3 = ldsB[b][t * 9 + 3], r4 = ldsB[b][t * 9 + 4], r5 = ldsB[b][t * 9 + 5],
                         r6 = ldsB[b][t * 9 + 6], r7 = ldsB[b][t * 9 + 7], r8 = ldsB[b][t * 9 + 8];
            chain_translation_q(r0, r1, r2, r3, r4, r5, r6, r7, r8, tgx, tgy, tgz);
        }
        const float d0 = tax - tgx, d1 = tay - tgy, d2 = taz - tgz;
        acc += d0 * d0 + d1 * d1 + d2 * d2;
    }

    // single-wave reduction
#pragma unroll
    for (int off = 32; off > 0; off >>= 1)
        acc += __shfl_down(acc, off, 64);
    if (t == 0) {
        const float scaled = acc * (1.0f / (262144.0f * 6.0f));
        // 1024 blocks x 2 device-scope fp32 atomics, spread over the kernel's
        // lifetime as blocks retire. vel_loss == pos_loss (gt_prev cancels).
        atomicAdd(&out[0], scaled);
        atomicAdd(&out[1], scaled);
    }
}

extern "C" void kernel_launch(void* const* d_in, const int* in_sizes, int n_in,
                              void* d_out, int out_size, void* d_ws, size_t ws_size,
                              hipStream_t stream) {
    const float* output_pose = (const float*)d_in[0];
    const float* gt_pose     = (const float*)d_in[1];
    // d_in[2] (gt_prev_pose) cancels algebraically: vel_loss == pos_loss.
    float* out = (float*)d_out;

    // Accumulator outputs must start at zero every replay (graph-legal async memset).
    hipMemsetAsync(out, 0, 2 * sizeof(float), stream);
    fk_loss_fused<<<NBLK, BLOCK, 0, stream>>>(output_pose, gt_pose, out);
}

// Round 11
// 28.764 us; speedup vs baseline: 3.1421x; 1.8307x over previous
//
#include <hip/hip_runtime.h>

#define NPOSE  262144
#define NCHAIN (NPOSE * 2)     // two independent FK chains per pose
#define BLOCK  64              // single-wave blocks
#define CPB    64              // chains per block
#define NBLK   (NCHAIN / CPB)  // 8192

typedef __attribute__((address_space(1))) void glb_void_t;
typedef __attribute__((address_space(3))) void lds_void_t;

// One FK step: 3x3 row-major elements e0..e8, cols c0=(e0,e3,e6),
// c1=(e1,e4,e7), t=(e2,e5,e8), R=[cross(c0,c1)|c0|c1]: v <- t + R*v
__device__ __forceinline__ void fk_step(float e0, float e1, float e2,
                                        float e3, float e4, float e5,
                                        float e6, float e7, float e8,
                                        float& v0, float& v1, float& v2) {
    const float x0 = e3 * e7 - e6 * e4;
    const float x1 = e6 * e1 - e0 * e7;
    const float x2 = e0 * e4 - e3 * e1;
    const float w0 = e2 + x0 * v0 + e0 * v1 + e1 * v2;
    const float w1 = e5 + x1 * v0 + e3 * v1 + e4 * v2;
    const float w2 = e8 + x2 * v0 + e6 * v1 + e7 * v2;
    v0 = w0; v1 = w1; v2 = w2;
}

// Chain of 4 matrices packed as 9 float4. translation = t0+R0*(t1+R1*(t2+R2*t3)).
// All by-value scalars: no local arrays, no pointers into aggregates (no scratch).
__device__ __forceinline__ void chain_translation_q(
        float4 q0, float4 q1, float4 q2, float4 q3, float4 q4,
        float4 q5, float4 q6, float4 q7, float4 q8,
        float& v0, float& v1, float& v2) {
    v0 = q7.y; v1 = q8.x; v2 = q8.w;                       // t3 = (p29,p32,p35)
    fk_step(q4.z, q4.w, q5.x, q5.y, q5.z, q5.w, q6.x, q6.y, q6.z, v0, v1, v2);  // m2
    fk_step(q2.y, q2.z, q2.w, q3.x, q3.y, q3.z, q3.w, q4.x, q4.y, v0, v1, v2);  // m1
    fk_step(q0.x, q0.y, q0.z, q0.w, q1.x, q1.y, q1.z, q1.w, q2.x, v0, v1, v2);  // m0
}

__global__ __launch_bounds__(BLOCK) void fk_loss_kernel(const float* __restrict__ outp,
                                                        const float* __restrict__ gtp,
                                                        float* __restrict__ partials) {
    // Two linear float4 LDS buffers; rows of 9 float4 (144B) per chain.
    // global_load_lds: LDS dest = uniform base + lane*16 -> ldsX[i*64 + lane];
    // global src per-lane contiguous -> perfectly coalesced. Zero VGPRs staged.
    __shared__ float4 ldsA[CPB * 9];       // 9216 B
    __shared__ float4 ldsB[CPB * 9];       // 9216 B  (total 18432 -> 8 blocks/CU)
    const int t = threadIdx.x;
    const size_t base4 = (size_t)blockIdx.x * (CPB * 9);
    const float4* __restrict__ ga = reinterpret_cast<const float4*>(outp) + base4;
    const float4* __restrict__ gb = reinterpret_cast<const float4*>(gtp) + base4;

#pragma unroll
    for (int i = 0; i < 9; ++i)
        __builtin_amdgcn_global_load_lds((glb_void_t*)(ga + t + 64 * i),
                                         (lds_void_t*)(&ldsA[i * 64]), 16, 0, 0);
#pragma unroll
    for (int i = 0; i < 9; ++i)
        __builtin_amdgcn_global_load_lds((glb_void_t*)(gb + t + 64 * i),
                                         (lds_void_t*)(&ldsB[i * 64]), 16, 0, 0);

    __syncthreads();   // drains vmcnt(0): all 18 DMAs landed

    // Transpose-read own chain (bank-uniform b128), FK A.
    float tax, tay, taz;
    {
        const float4 r0 = ldsA[t * 9 + 0], r1 = ldsA[t * 9 + 1], r2 = ldsA[t * 9 + 2],
                     r3 = ldsA[t * 9 + 3], r4 = ldsA[t * 9 + 4], r5 = ldsA[t * 9 + 5],
                     r6 = ldsA[t * 9 + 6], r7 = ldsA[t * 9 + 7], r8 = ldsA[t * 9 + 8];
        chain_translation_q(r0, r1, r2, r3, r4, r5, r6, r7, r8, tax, tay, taz);
    }
    // FK B (separate buffer: no barrier needed).
    float tgx, tgy, tgz;
    {
        const float4 r0 = ldsB[t * 9 + 0], r1 = ldsB[t * 9 + 1], r2 = ldsB[t * 9 + 2],
                     r3 = ldsB[t * 9 + 3], r4 = ldsB[t * 9 + 4], r5 = ldsB[t * 9 + 5],
                     r6 = ldsB[t * 9 + 6], r7 = ldsB[t * 9 + 7], r8 = ldsB[t * 9 + 8];
        chain_translation_q(r0, r1, r2, r3, r4, r5, r6, r7, r8, tgx, tgy, tgz);
    }

    const float d0 = tax - tgx, d1 = tay - tgy, d2 = taz - tgz;
    float acc = d0 * d0 + d1 * d1 + d2 * d2;

    // single-wave reduction
#pragma unroll
    for (int off = 32; off > 0; off >>= 1)
        acc += __shfl_down(acc, off, 64);
    if (t == 0) partials[blockIdx.x] = acc;
}

__global__ __launch_bounds__(512) void reduce_kernel(const float* __restrict__ partials,
                                                     float* __restrict__ out) {
    const int t = threadIdx.x;
    const float4* __restrict__ p4 = reinterpret_cast<const float4*>(partials); // 2048 float4
    float s = 0.0f;
#pragma unroll
    for (int i = 0; i < 4; ++i) {
        const float4 v = p4[t + 512 * i];
        s += v.x + v.y + v.z + v.w;
    }
#pragma unroll
    for (int off = 32; off > 0; off >>= 1)
        s += __shfl_down(s, off, 64);
    __shared__ float smem[8];
    const int lane = t & 63, wid = t >> 6;
    if (lane == 0) smem[wid] = s;
    __syncthreads();
    if (t == 0) {
        float tot = 0.0f;
#pragma unroll
        for (int w = 0; w < 8; ++w) tot += smem[w];
        const float mean = tot / (262144.0f * 6.0f);
        out[0] = mean;  // pos_loss
        out[1] = mean;  // vel_loss == pos_loss (gt_prev cancels algebraically)
    }
}

extern "C" void kernel_launch(void* const* d_in, const int* in_sizes, int n_in,
                              void* d_out, int out_size, void* d_ws, size_t ws_size,
                              hipStream_t stream) {
    const float* output_pose = (const float*)d_in[0];
    const float* gt_pose     = (const float*)d_in[1];
    // d_in[2] (gt_prev_pose) cancels algebraically: vel_loss == pos_loss.
    float* out = (float*)d_out;
    float* partials = (float*)d_ws;   // 8192 floats = 32 KB

    fk_loss_kernel<<<NBLK, BLOCK, 0, stream>>>(output_pose, gt_pose, partials);
    reduce_kernel<<<1, 512, 0, stream>>>(partials, out);
}